// Round 1
// baseline (1321.693 us; speedup 1.0000x reference)
//
#include <hip/hip_runtime.h>
#include <hip/hip_bf16.h>

#define H      1024
#define C      32
#define B      2048
#define TWOH   2048
#define M_TOT  (B * C)      // 65536

#define BM 128
#define BN 128
#define BK 64
#define NKSTEP (H / BK)     // 16

typedef float f32x4  __attribute__((ext_vector_type(4)));
typedef short bf16x8 __attribute__((ext_vector_type(8)));

__device__ __forceinline__ unsigned short f2bf(float f) {
    unsigned u = __float_as_uint(f);
    unsigned rounding = 0x7fffu + ((u >> 16) & 1u);   // RNE
    return (unsigned short)((u + rounding) >> 16);
}

// ---------------------------------------------------------------- cast W_in
__global__ __launch_bounds__(256) void cast_w(const float* __restrict__ W,
                                              unsigned short* __restrict__ Wb) {
    int i = blockIdx.x * 256 + threadIdx.x;           // over (TWOH*H)/4 float4s
    float4 v = reinterpret_cast<const float4*>(W)[i];
    ushort4 o;
    o.x = f2bf(v.x); o.y = f2bf(v.y); o.z = f2bf(v.z); o.w = f2bf(v.w);
    reinterpret_cast<ushort4*>(Wb)[i] = o;
}

// ------------------------------------------------------- fused scores GEMM
// A = cell_states [M_TOT][H] f32 (rows are (b,c); b = row>>5)
// Ac = cell_state_c [B][H] f32 — 4 rows per m-tile folded in as extra A2 tile
// Wb = bf16 W_in [TWOH][H]
// scores[row] += sum_k tanh(projc[b][k] + projcell[row][k]) * v[k]   (this wg's 128 k-cols)
__global__ __launch_bounds__(256) void score_gemm(const float* __restrict__ A,
                                                  const float* __restrict__ Ac,
                                                  const unsigned short* __restrict__ Wb,
                                                  const float* __restrict__ v,
                                                  float* __restrict__ scores) {
    __shared__ __align__(16) unsigned short As[BM * BK];
    __shared__ __align__(16) unsigned short Bs[BN * BK];
    __shared__ __align__(16) unsigned short A2s[16 * BK];

    const int tid  = threadIdx.x;
    const int wave = tid >> 6;
    const int lane = tid & 63;
    const int wm = wave >> 1, wn = wave & 1;
    const int lrow = lane >> 4, lcol = lane & 15;

    // XCD-bijective swizzle: 8192 wgs, consecutive wgs round-robin XCDs (%8).
    // Within an XCD, the 16 n-tiles of an m-tile are consecutive -> A tile L2 reuse.
    int wg  = blockIdx.x;
    int idx = wg >> 3, x = wg & 7;
    const int mt = x * 64 + (idx >> 4);   // [0,512)
    const int nt = idx & 15;              // [0,16)
    const int m_base = mt * BM;
    const int n_base = nt * BN;
    const int b0 = m_base >> 5;           // 4 b's per m-tile

    // zero the unused rows 4..15 of the cell_state_c sub-tile (once)
    if (tid < 192) {
        int r = 4 + (tid >> 4), c4 = (tid & 15) * 4;
        *reinterpret_cast<uint2*>(&A2s[r * BK + c4]) = make_uint2(0u, 0u);
    }

    const int arow = tid >> 4;            // 0..15
    const int acol = (tid & 15) * 4;      // 0,4,..,60
    const int brow = tid >> 3;            // 0..31
    const int bcol = (tid & 7) * 8;       // 0,8,..,56

    float4 sA[8];
    uint4  sB[4];
    float4 sA2;

    auto loadTile = [&](int k0) {
        #pragma unroll
        for (int i = 0; i < 8; ++i) {
            int r = arow + 16 * i;
            sA[i] = *reinterpret_cast<const float4*>(&A[(size_t)(m_base + r) * H + k0 + acol]);
        }
        #pragma unroll
        for (int i = 0; i < 4; ++i) {
            int r = brow + 32 * i;
            sB[i] = *reinterpret_cast<const uint4*>(&Wb[(size_t)(n_base + r) * H + k0 + bcol]);
        }
        if (tid < 64) {
            int r = tid >> 4;             // 0..3
            sA2 = *reinterpret_cast<const float4*>(&Ac[(size_t)(b0 + r) * H + k0 + acol]);
        }
    };

    auto writeTile = [&]() {
        #pragma unroll
        for (int i = 0; i < 8; ++i) {
            int r = arow + 16 * i;
            ushort4 o;
            o.x = f2bf(sA[i].x); o.y = f2bf(sA[i].y); o.z = f2bf(sA[i].z); o.w = f2bf(sA[i].w);
            *reinterpret_cast<ushort4*>(&As[r * BK + (acol ^ ((r & 7) << 3))]) = o;
        }
        #pragma unroll
        for (int i = 0; i < 4; ++i) {
            int r = brow + 32 * i;
            *reinterpret_cast<uint4*>(&Bs[r * BK + (bcol ^ ((r & 7) << 3))]) = sB[i];
        }
        if (tid < 64) {
            int r = tid >> 4;
            ushort4 o;
            o.x = f2bf(sA2.x); o.y = f2bf(sA2.y); o.z = f2bf(sA2.z); o.w = f2bf(sA2.w);
            *reinterpret_cast<ushort4*>(&A2s[r * BK + (acol ^ ((r & 7) << 3))]) = o;
        }
    };

    f32x4 acc[4][4] = {};
    f32x4 eacc[4]   = {};

    loadTile(0);
    for (int kt = 0; kt < NKSTEP; ++kt) {
        __syncthreads();                  // LDS free (prev consumers done / init done)
        writeTile();
        __syncthreads();                  // LDS ready
        if (kt + 1 < NKSTEP) loadTile((kt + 1) * BK);   // overlap with MFMA below

        #pragma unroll
        for (int kk = 0; kk < 2; ++kk) {
            const int kb = kk * 32 + lrow * 8;          // elem col in [0,64)
            bf16x8 a[4], bb[4], a2;
            {
                int r = lcol;
                a2 = *reinterpret_cast<bf16x8*>(&A2s[r * BK + (kb ^ ((r & 7) << 3))]);
            }
            #pragma unroll
            for (int mf = 0; mf < 4; ++mf) {
                int r = wm * 64 + mf * 16 + lcol;
                a[mf] = *reinterpret_cast<bf16x8*>(&As[r * BK + (kb ^ ((r & 7) << 3))]);
            }
            #pragma unroll
            for (int nf = 0; nf < 4; ++nf) {
                int r = wn * 64 + nf * 16 + lcol;
                bb[nf] = *reinterpret_cast<bf16x8*>(&Bs[r * BK + (kb ^ ((r & 7) << 3))]);
            }
            #pragma unroll
            for (int nf = 0; nf < 4; ++nf)
                eacc[nf] = __builtin_amdgcn_mfma_f32_16x16x32_bf16(a2, bb[nf], eacc[nf], 0, 0, 0);
            #pragma unroll
            for (int mf = 0; mf < 4; ++mf)
                #pragma unroll
                for (int nf = 0; nf < 4; ++nf)
                    acc[mf][nf] = __builtin_amdgcn_mfma_f32_16x16x32_bf16(a[mf], bb[nf], acc[mf][nf], 0, 0, 0);
        }
    }

    // -------- epilogue: tanh(acc + projc) * v, reduce over cols, atomicAdd
    float vv[4];
    #pragma unroll
    for (int nf = 0; nf < 4; ++nf)
        vv[nf] = v[n_base + wn * 64 + nf * 16 + lcol];

    float sp[4][4] = {};
    #pragma unroll
    for (int mf = 0; mf < 4; ++mf) {
        const int b_local = (wm * 64 + mf * 16) >> 5;   // compile-time per mf
        #pragma unroll
        for (int nf = 0; nf < 4; ++nf) {
            // projc value for (this tile's b, this lane's col) lives in lane lcol, reg b_local
            float pc = __shfl(eacc[nf][b_local], lcol, 64);
            #pragma unroll
            for (int j = 0; j < 4; ++j) {
                float xv = acc[mf][nf][j] + pc;
                xv = fminf(fmaxf(xv, -15.f), 15.f);
                float e  = __expf(2.f * xv);
                float th = 1.f - 2.f / (e + 1.f);
                sp[mf][j] += th * vv[nf];
            }
        }
    }

    #pragma unroll
    for (int mf = 0; mf < 4; ++mf) {
        #pragma unroll
        for (int j = 0; j < 4; ++j) {
            float s = sp[mf][j];
            s += __shfl_xor(s, 1, 16);
            s += __shfl_xor(s, 2, 16);
            s += __shfl_xor(s, 4, 16);
            s += __shfl_xor(s, 8, 16);
            if (lcol == 0)
                atomicAdd(&scores[m_base + wm * 64 + mf * 16 + lrow * 4 + j], s);
        }
    }
}

// --------------------------------------------- softmax over C + weighted sum
__global__ __launch_bounds__(256) void softmax_out(const float* __restrict__ scores,
                                                   const float* __restrict__ cs,
                                                   float* __restrict__ out) {
    __shared__ float p_sh[C];
    const int b = blockIdx.x;
    const int t = threadIdx.x;

    if (t < C) {
        float s = scores[b * C + t];
        float m = s;
        #pragma unroll
        for (int d = 16; d >= 1; d >>= 1) m = fmaxf(m, __shfl_xor(m, d, 32));
        float e = __expf(s - m);
        float sum = e;
        #pragma unroll
        for (int d = 16; d >= 1; d >>= 1) sum += __shfl_xor(sum, d, 32);
        float p = e / sum;
        p_sh[t] = p;
        out[(size_t)B * H + (size_t)b * C + t] = p;
    }
    __syncthreads();

    const int h0 = t * 4;
    float4 o = {0.f, 0.f, 0.f, 0.f};
    #pragma unroll 8
    for (int c = 0; c < C; ++c) {
        float4 xv = *reinterpret_cast<const float4*>(&cs[((size_t)(b * C + c)) * H + h0]);
        float p = p_sh[c];
        o.x += p * xv.x; o.y += p * xv.y; o.z += p * xv.z; o.w += p * xv.w;
    }
    *reinterpret_cast<float4*>(&out[(size_t)b * H + h0]) = o;
}

// --------------------------------------------------------------------- host
extern "C" void kernel_launch(void* const* d_in, const int* in_sizes, int n_in,
                              void* d_out, int out_size, void* d_ws, size_t ws_size,
                              hipStream_t stream) {
    const float* csc = (const float*)d_in[0];   // cell_state_c [B][H]
    const float* cs  = (const float*)d_in[1];   // cell_states  [B][C][H]
    const float* W   = (const float*)d_in[2];   // W_in [2H][H]
    const float* v   = (const float*)d_in[3];   // atten_v [2H]
    float* out = (float*)d_out;

    unsigned short* Wb = (unsigned short*)d_ws;                         // 4 MB bf16 W
    float* scores = (float*)((char*)d_ws + (size_t)TWOH * H * 2);       // 256 KB

    cast_w<<<(TWOH * H / 4) / 256, 256, 0, stream>>>(W, Wb);
    hipMemsetAsync(scores, 0, M_TOT * sizeof(float), stream);
    score_gemm<<<(M_TOT / BM) * (TWOH / BN), 256, 0, stream>>>(cs, csc, Wb, v, scores);
    softmax_out<<<B, 256, 0, stream>>>(scores, cs, out);
}

// Round 3
// 947.927 us; speedup vs baseline: 1.3943x; 1.3943x over previous
//
#include <hip/hip_runtime.h>
#include <hip/hip_bf16.h>

#define H      1024
#define C      32
#define B      2048
#define TWOH   2048
#define M_TOT  (B * C)      // 65536

#define BM 128
#define BN 128
#define BK 64
#define NKSTEP (H / BK)     // 16

typedef float f32x4  __attribute__((ext_vector_type(4)));
typedef short bf16x8 __attribute__((ext_vector_type(8)));

__device__ __forceinline__ unsigned short f2bf(float f) {
    unsigned u = __float_as_uint(f);
    unsigned rounding = 0x7fffu + ((u >> 16) & 1u);   // RNE
    return (unsigned short)((u + rounding) >> 16);
}

// ============================================================== FAST PATH
// Tiled-swizzled bf16 layout: matrix [R][1024] split into tiles of 128 rows
// x 64 cols; tile (rt,kt) is 8192 contiguous bf16 (16 KB) at (rt*16+kt)*8192;
// element (rr,cc) at rr*64 + (cc ^ ((rr&7)<<3)).  This makes global_load_lds
// (linear LDS dest) produce exactly the swizzled LDS image the ds_read_b128
// fragment reads expect (2-way-max bank aliasing = free).

__global__ __launch_bounds__(256) void cast_tiled(const float* __restrict__ src,
                                                  unsigned short* __restrict__ dst) {
    const int t  = threadIdx.x;
    const int tileid = blockIdx.x;
    const int rt = tileid >> 4, kt = tileid & 15;
    const int rr = t >> 1, c0 = (t & 1) * 32;
    const float* s = src + (size_t)(rt * 128 + rr) * 1024 + kt * 64 + c0;
    unsigned short* d = dst + (size_t)tileid * 8192 + rr * 64;
    #pragma unroll
    for (int i = 0; i < 8; ++i) {
        float4 f = *reinterpret_cast<const float4*>(s + i * 4);
        ushort4 o;
        o.x = f2bf(f.x); o.y = f2bf(f.y); o.z = f2bf(f.z); o.w = f2bf(f.w);
        *reinterpret_cast<ushort4*>(&d[(c0 + i * 4) ^ ((rr & 7) << 3)]) = o;
    }
}

// EPI=0: plain GEMM, store acc -> outp[row*2048+col]   (proj_c = csc @ W^T)
// EPI=1: fused scores: acc + pc -> tanh -> *v -> col-reduce -> partial slabs
template<int EPI>
__global__ __launch_bounds__(256) void gemm_fast(const unsigned short* __restrict__ At,
                                                 const unsigned short* __restrict__ Bt,
                                                 const float* __restrict__ pc,
                                                 const float* __restrict__ v,
                                                 float* __restrict__ outp) {
    __shared__ __align__(16) unsigned short As[BM * BK];
    __shared__ __align__(16) unsigned short Bs[BN * BK];

    const int tid  = threadIdx.x;
    const int wave = tid >> 6;
    const int lane = tid & 63;
    const int wm = wave >> 1, wn = wave & 1;
    const int lrow = lane >> 4, lcol = lane & 15;

    int mt, nt;
    if constexpr (EPI == 0) {
        mt = blockIdx.x >> 4; nt = blockIdx.x & 15;      // 256 wgs, no swizzle
    } else {
        // XCD-bijective swizzle (8192 wgs = 8*1024): n-tiles of one m-tile
        // stay consecutive on one XCD -> A tile L2 reuse.
        int wg = blockIdx.x;
        int idx = wg >> 3, x = wg & 7;
        mt = x * 64 + (idx >> 4);
        nt = idx & 15;
    }
    const int m_base = mt * BM;
    const int n_base = nt * BN;

    f32x4 acc[4][4] = {};

    float pcv[4][4];
    if constexpr (EPI == 1) {
        #pragma unroll
        for (int mf = 0; mf < 4; ++mf) {
            const int bX = (m_base >> 5) + wm * 2 + (mf >> 1);  // b of this 16-row frag
            #pragma unroll
            for (int nf = 0; nf < 4; ++nf)
                pcv[mf][nf] = pc[(size_t)bX * TWOH + n_base + wn * 64 + nf * 16 + lcol];
        }
    }

    for (int kt = 0; kt < NKSTEP; ++kt) {
        const unsigned short* aSrc = At + (size_t)(mt * 16 + kt) * 8192 + tid * 8;
        const unsigned short* bSrc = Bt + (size_t)(nt * 16 + kt) * 8192 + tid * 8;
        __syncthreads();   // LDS free (prev readers done)
        #pragma unroll
        for (int i = 0; i < 4; ++i)
            __builtin_amdgcn_global_load_lds(
                (const __attribute__((address_space(1))) void*)(aSrc + i * 2048),
                (__attribute__((address_space(3))) void*)(&As[wave * 512 + i * 2048]),
                16, 0, 0);
        #pragma unroll
        for (int i = 0; i < 4; ++i)
            __builtin_amdgcn_global_load_lds(
                (const __attribute__((address_space(1))) void*)(bSrc + i * 2048),
                (__attribute__((address_space(3))) void*)(&Bs[wave * 512 + i * 2048]),
                16, 0, 0);
        __syncthreads();   // own vmcnt drained per wave -> all tile data in LDS

        #pragma unroll
        for (int kk = 0; kk < 2; ++kk) {
            const int kb = kk * 32 + lrow * 8;
            bf16x8 a[4], bb[4];
            #pragma unroll
            for (int mf = 0; mf < 4; ++mf) {
                int r = wm * 64 + mf * 16 + lcol;
                a[mf] = *reinterpret_cast<const bf16x8*>(&As[r * BK + (kb ^ ((r & 7) << 3))]);
            }
            #pragma unroll
            for (int nf = 0; nf < 4; ++nf) {
                int r = wn * 64 + nf * 16 + lcol;
                bb[nf] = *reinterpret_cast<const bf16x8*>(&Bs[r * BK + (kb ^ ((r & 7) << 3))]);
            }
            #pragma unroll
            for (int mf = 0; mf < 4; ++mf)
                #pragma unroll
                for (int nf = 0; nf < 4; ++nf)
                    acc[mf][nf] = __builtin_amdgcn_mfma_f32_16x16x32_bf16(a[mf], bb[nf], acc[mf][nf], 0, 0, 0);
        }
    }

    if constexpr (EPI == 0) {
        #pragma unroll
        for (int mf = 0; mf < 4; ++mf)
            #pragma unroll
            for (int nf = 0; nf < 4; ++nf)
                #pragma unroll
                for (int j = 0; j < 4; ++j)
                    outp[(size_t)(m_base + wm * 64 + mf * 16 + lrow * 4 + j) * TWOH
                         + n_base + wn * 64 + nf * 16 + lcol] = acc[mf][nf][j];
    } else {
        float vv[4];
        #pragma unroll
        for (int nf = 0; nf < 4; ++nf)
            vv[nf] = v[n_base + wn * 64 + nf * 16 + lcol];

        float sp[4][4] = {};
        #pragma unroll
        for (int mf = 0; mf < 4; ++mf)
            #pragma unroll
            for (int nf = 0; nf < 4; ++nf)
                #pragma unroll
                for (int j = 0; j < 4; ++j) {
                    float xv = acc[mf][nf][j] + pcv[mf][nf];
                    xv = fminf(fmaxf(xv, -15.f), 15.f);
                    float e  = __expf(2.f * xv);
                    float th = 1.f - 2.f / (e + 1.f);
                    sp[mf][j] += th * vv[nf];
                }

        #pragma unroll
        for (int mf = 0; mf < 4; ++mf)
            #pragma unroll
            for (int j = 0; j < 4; ++j) {
                float s = sp[mf][j];
                s += __shfl_xor(s, 1, 16);
                s += __shfl_xor(s, 2, 16);
                s += __shfl_xor(s, 4, 16);
                s += __shfl_xor(s, 8, 16);
                if (lcol == 0)
                    outp[(size_t)(nt * 2 + wn) * M_TOT
                         + m_base + wm * 64 + mf * 16 + lrow * 4 + j] = s;
            }
    }
}

// softmax over C + weighted sum; scores = sum of 32 partial slabs
__global__ __launch_bounds__(256) void softmax_out2(const float* __restrict__ partial,
                                                    const float* __restrict__ cs,
                                                    float* __restrict__ out) {
    __shared__ float p_sh[C];
    const int b = blockIdx.x;
    const int t = threadIdx.x;

    if (t < C) {
        float s = 0.f;
        #pragma unroll 8
        for (int sl = 0; sl < 32; ++sl)
            s += partial[(size_t)sl * M_TOT + b * C + t];
        float m = s;
        #pragma unroll
        for (int d = 16; d >= 1; d >>= 1) m = fmaxf(m, __shfl_xor(m, d, 32));
        float e = __expf(s - m);
        float sum = e;
        #pragma unroll
        for (int d = 16; d >= 1; d >>= 1) sum += __shfl_xor(sum, d, 32);
        float p = e / sum;
        p_sh[t] = p;
        out[(size_t)B * H + (size_t)b * C + t] = p;
    }
    __syncthreads();

    const int h0 = t * 4;
    float4 o = {0.f, 0.f, 0.f, 0.f};
    #pragma unroll 8
    for (int c = 0; c < C; ++c) {
        float4 xv = *reinterpret_cast<const float4*>(&cs[((size_t)(b * C + c)) * H + h0]);
        float p = p_sh[c];
        o.x += p * xv.x; o.y += p * xv.y; o.z += p * xv.z; o.w += p * xv.w;
    }
    *reinterpret_cast<float4*>(&out[(size_t)b * H + h0]) = o;
}

// ========================================================== FALLBACK PATH
// (verbatim round-1 kernels — already validated; used when ws is small)

__global__ __launch_bounds__(256) void cast_w(const float* __restrict__ W,
                                              unsigned short* __restrict__ Wb) {
    int i = blockIdx.x * 256 + threadIdx.x;
    float4 v = reinterpret_cast<const float4*>(W)[i];
    ushort4 o;
    o.x = f2bf(v.x); o.y = f2bf(v.y); o.z = f2bf(v.z); o.w = f2bf(v.w);
    reinterpret_cast<ushort4*>(Wb)[i] = o;
}

__global__ __launch_bounds__(256) void score_gemm(const float* __restrict__ A,
                                                  const float* __restrict__ Ac,
                                                  const unsigned short* __restrict__ Wb,
                                                  const float* __restrict__ v,
                                                  float* __restrict__ scores) {
    __shared__ __align__(16) unsigned short As[BM * BK];
    __shared__ __align__(16) unsigned short Bs[BN * BK];
    __shared__ __align__(16) unsigned short A2s[16 * BK];

    const int tid  = threadIdx.x;
    const int wave = tid >> 6;
    const int lane = tid & 63;
    const int wm = wave >> 1, wn = wave & 1;
    const int lrow = lane >> 4, lcol = lane & 15;

    int wg  = blockIdx.x;
    int idx = wg >> 3, x = wg & 7;
    const int mt = x * 64 + (idx >> 4);
    const int nt = idx & 15;
    const int m_base = mt * BM;
    const int n_base = nt * BN;
    const int b0 = m_base >> 5;

    if (tid < 192) {
        int r = 4 + (tid >> 4), c4 = (tid & 15) * 4;
        *reinterpret_cast<uint2*>(&A2s[r * BK + c4]) = make_uint2(0u, 0u);
    }

    const int arow = tid >> 4;
    const int acol = (tid & 15) * 4;
    const int brow = tid >> 3;
    const int bcol = (tid & 7) * 8;

    float4 sA[8];
    uint4  sB[4];
    float4 sA2;

    auto loadTile = [&](int k0) {
        #pragma unroll
        for (int i = 0; i < 8; ++i) {
            int r = arow + 16 * i;
            sA[i] = *reinterpret_cast<const float4*>(&A[(size_t)(m_base + r) * H + k0 + acol]);
        }
        #pragma unroll
        for (int i = 0; i < 4; ++i) {
            int r = brow + 32 * i;
            sB[i] = *reinterpret_cast<const uint4*>(&Wb[(size_t)(n_base + r) * H + k0 + bcol]);
        }
        if (tid < 64) {
            int r = tid >> 4;
            sA2 = *reinterpret_cast<const float4*>(&Ac[(size_t)(b0 + r) * H + k0 + acol]);
        }
    };

    auto writeTile = [&]() {
        #pragma unroll
        for (int i = 0; i < 8; ++i) {
            int r = arow + 16 * i;
            ushort4 o;
            o.x = f2bf(sA[i].x); o.y = f2bf(sA[i].y); o.z = f2bf(sA[i].z); o.w = f2bf(sA[i].w);
            *reinterpret_cast<ushort4*>(&As[r * BK + (acol ^ ((r & 7) << 3))]) = o;
        }
        #pragma unroll
        for (int i = 0; i < 4; ++i) {
            int r = brow + 32 * i;
            *reinterpret_cast<uint4*>(&Bs[r * BK + (bcol ^ ((r & 7) << 3))]) = sB[i];
        }
        if (tid < 64) {
            int r = tid >> 4;
            ushort4 o;
            o.x = f2bf(sA2.x); o.y = f2bf(sA2.y); o.z = f2bf(sA2.z); o.w = f2bf(sA2.w);
            *reinterpret_cast<ushort4*>(&A2s[r * BK + (acol ^ ((r & 7) << 3))]) = o;
        }
    };

    f32x4 acc[4][4] = {};
    f32x4 eacc[4]   = {};

    loadTile(0);
    for (int kt = 0; kt < NKSTEP; ++kt) {
        __syncthreads();
        writeTile();
        __syncthreads();
        if (kt + 1 < NKSTEP) loadTile((kt + 1) * BK);

        #pragma unroll
        for (int kk = 0; kk < 2; ++kk) {
            const int kb = kk * 32 + lrow * 8;
            bf16x8 a[4], bb[4], a2;
            {
                int r = lcol;
                a2 = *reinterpret_cast<bf16x8*>(&A2s[r * BK + (kb ^ ((r & 7) << 3))]);
            }
            #pragma unroll
            for (int mf = 0; mf < 4; ++mf) {
                int r = wm * 64 + mf * 16 + lcol;
                a[mf] = *reinterpret_cast<bf16x8*>(&As[r * BK + (kb ^ ((r & 7) << 3))]);
            }
            #pragma unroll
            for (int nf = 0; nf < 4; ++nf) {
                int r = wn * 64 + nf * 16 + lcol;
                bb[nf] = *reinterpret_cast<bf16x8*>(&Bs[r * BK + (kb ^ ((r & 7) << 3))]);
            }
            #pragma unroll
            for (int nf = 0; nf < 4; ++nf)
                eacc[nf] = __builtin_amdgcn_mfma_f32_16x16x32_bf16(a2, bb[nf], eacc[nf], 0, 0, 0);
            #pragma unroll
            for (int mf = 0; mf < 4; ++mf)
                #pragma unroll
                for (int nf = 0; nf < 4; ++nf)
                    acc[mf][nf] = __builtin_amdgcn_mfma_f32_16x16x32_bf16(a[mf], bb[nf], acc[mf][nf], 0, 0, 0);
        }
    }

    float vv[4];
    #pragma unroll
    for (int nf = 0; nf < 4; ++nf)
        vv[nf] = v[n_base + wn * 64 + nf * 16 + lcol];

    float sp[4][4] = {};
    #pragma unroll
    for (int mf = 0; mf < 4; ++mf) {
        const int b_local = (wm * 64 + mf * 16) >> 5;
        #pragma unroll
        for (int nf = 0; nf < 4; ++nf) {
            float pc = __shfl(eacc[nf][b_local], lcol, 64);
            #pragma unroll
            for (int j = 0; j < 4; ++j) {
                float xv = acc[mf][nf][j] + pc;
                xv = fminf(fmaxf(xv, -15.f), 15.f);
                float e  = __expf(2.f * xv);
                float th = 1.f - 2.f / (e + 1.f);
                sp[mf][j] += th * vv[nf];
            }
        }
    }

    #pragma unroll
    for (int mf = 0; mf < 4; ++mf) {
        #pragma unroll
        for (int j = 0; j < 4; ++j) {
            float s = sp[mf][j];
            s += __shfl_xor(s, 1, 16);
            s += __shfl_xor(s, 2, 16);
            s += __shfl_xor(s, 4, 16);
            s += __shfl_xor(s, 8, 16);
            if (lcol == 0)
                atomicAdd(&scores[m_base + wm * 64 + mf * 16 + lrow * 4 + j], s);
        }
    }
}

__global__ __launch_bounds__(256) void softmax_out(const float* __restrict__ scores,
                                                   const float* __restrict__ cs,
                                                   float* __restrict__ out) {
    __shared__ float p_sh[C];
    const int b = blockIdx.x;
    const int t = threadIdx.x;

    if (t < C) {
        float s = scores[b * C + t];
        float m = s;
        #pragma unroll
        for (int d = 16; d >= 1; d >>= 1) m = fmaxf(m, __shfl_xor(m, d, 32));
        float e = __expf(s - m);
        float sum = e;
        #pragma unroll
        for (int d = 16; d >= 1; d >>= 1) sum += __shfl_xor(sum, d, 32);
        float p = e / sum;
        p_sh[t] = p;
        out[(size_t)B * H + (size_t)b * C + t] = p;
    }
    __syncthreads();

    const int h0 = t * 4;
    float4 o = {0.f, 0.f, 0.f, 0.f};
    #pragma unroll 8
    for (int c = 0; c < C; ++c) {
        float4 xv = *reinterpret_cast<const float4*>(&cs[((size_t)(b * C + c)) * H + h0]);
        float p = p_sh[c];
        o.x += p * xv.x; o.y += p * xv.y; o.z += p * xv.z; o.w += p * xv.w;
    }
    *reinterpret_cast<float4*>(&out[(size_t)b * H + h0]) = o;
}

// --------------------------------------------------------------------- host
extern "C" void kernel_launch(void* const* d_in, const int* in_sizes, int n_in,
                              void* d_out, int out_size, void* d_ws, size_t ws_size,
                              hipStream_t stream) {
    const float* csc = (const float*)d_in[0];   // cell_state_c [B][H]
    const float* cs  = (const float*)d_in[1];   // cell_states  [B][C][H]
    const float* W   = (const float*)d_in[2];   // W_in [2H][H]
    const float* v   = (const float*)d_in[3];   // atten_v [2H]
    float* out = (float*)d_out;

    // fast-path ws layout (bytes):
    //   Wb_tiled   @ 0          4 MB   (bf16 W, tiled-swizzled)
    //   Cscb_tiled @ 4194304    4 MB   (bf16 cell_state_c, tiled-swizzled)
    //   pc         @ 8388608   16 MB   (proj_c f32 [B][2H])
    //   partial    @ 25165824   8 MB   (32 slabs x 65536 f32)
    //   Ab_tiled   @ 33554432 134 MB   (bf16 cell_states, tiled-swizzled)
    const size_t FAST_WS = 167772160ull;   // 160 MB

    if (ws_size >= FAST_WS) {
        unsigned short* Wb = (unsigned short*)d_ws;
        unsigned short* Cb = (unsigned short*)((char*)d_ws + 4194304);
        float* pcbuf       = (float*)((char*)d_ws + 8388608);
        float* partial     = (float*)((char*)d_ws + 25165824);
        unsigned short* Ab = (unsigned short*)((char*)d_ws + 33554432);

        cast_tiled<<<256,  256, 0, stream>>>(W,   Wb);   // 16 row-tiles x 16
        cast_tiled<<<256,  256, 0, stream>>>(csc, Cb);
        cast_tiled<<<8192, 256, 0, stream>>>(cs,  Ab);   // 512 row-tiles x 16
        gemm_fast<0><<<256,  256, 0, stream>>>(Cb, Wb, nullptr, nullptr, pcbuf);
        gemm_fast<1><<<8192, 256, 0, stream>>>(Ab, Wb, pcbuf, v, partial);
        softmax_out2<<<B, 256, 0, stream>>>(partial, cs, out);
    } else {
        unsigned short* Wb = (unsigned short*)d_ws;
        float* scores = (float*)((char*)d_ws + (size_t)TWOH * H * 2);
        cast_w<<<(TWOH * H / 4) / 256, 256, 0, stream>>>(W, Wb);
        hipMemsetAsync(scores, 0, M_TOT * sizeof(float), stream);
        score_gemm<<<(M_TOT / BM) * (TWOH / BN), 256, 0, stream>>>(cs, csc, Wb, v, scores);
        softmax_out<<<B, 256, 0, stream>>>(scores, cs, out);
    }
}